// Round 16
// baseline (7905.254 us; speedup 1.0000x reference)
//
#include <hip/hip_runtime.h>
#include <cstdint>
#include <cstring>
#include <vector>
#include <algorithm>

// ---------------------------------------------------------------------------
// GRASPLayer round 16:
//  - GRU: 2 syncs/step (3-buffer single-stage combine, bit-exact addition
//    tree), x prefetched into registers across the step, unroll-2 W loads.
//  - kmeans: 100 launches, one per Lloyd iteration; assign (r12 verbatim) +
//    ticket-elected last-block update (fixed-order, bit-identical).
// ---------------------------------------------------------------------------

namespace {
constexpr int Nn = 2048;
constexpr int Tt = 128;
constexpr int Dd = 256;
constexpr int Hh = 256;
constexpr int Kk = 12;
constexpr int MAXIT = 100;
}

struct IdxArgs { int v[Kk]; };

typedef float v2f __attribute__((ext_vector_type(2)));

__device__ __forceinline__ float sigm(float x) { return 1.0f / (1.0f + expf(-x)); }

#define PKFMA(A, X, W) \
  asm("v_pk_fma_f32 %0, %1, %2, %0" : "+v"(A) : "v"(X), "v"(W))
#define LO2(V) ((v2f){(V).x, (V).y})
#define HI2(V) ((v2f){(V).z, (V).w})

// ---------------------------------------------------------------------------
// Pack Wih/Whh [3*256 x 256] into pk[k4][g][c][4] (float4 = 4 adjacent k of
// column c), g in {ihr,ihz,ihn,hhr,hhz,hhn}.
__global__ __launch_bounds__(64) void pack_w(
    const float* __restrict__ Wih, const float* __restrict__ Whh,
    float* __restrict__ pk)
{
  const int j = blockIdx.x;            // 0..767 = w-row (g*256 + c)
  const int k4 = threadIdx.x;          // 0..63
  const int g = j >> 8, c = j & 255;
  float4 vih = *(const float4*)&Wih[(size_t)j * 256 + k4 * 4];
  float4 vhh = *(const float4*)&Whh[(size_t)j * 256 + k4 * 4];
  *(float4*)&pk[(((size_t)k4 * 6 + g) * 256 + c) * 4]       = vih;
  *(float4*)&pk[(((size_t)k4 * 6 + 3 + g) * 256 + c) * 4]   = vhh;
}

// ---------------------------------------------------------------------------
// 256 blocks x 512 threads; block owns 8 rows. Thread (cp, q) accumulates
// cols {cp, cp+128} over k-quarter q. 2 syncs/step; combine tree bit-exact
// with r12/r14: s = (q0+q1) + (q2+q3).
__global__ __launch_bounds__(512, 1) void gru_q(
    const float* __restrict__ x, const int* __restrict__ len,
    const float* __restrict__ pk,
    const float* __restrict__ bih, const float* __restrict__ bhh,
    float* __restrict__ hfin)
{
  __shared__ alignas(16) float xls[8][260];
  __shared__ alignas(16) float hls[8][260];
  __shared__ float4 pbA[8][256];                // q1 partials (32 KB)
  __shared__ float4 pbB[8][256];                // q2 partials
  __shared__ float4 pbC[8][256];                // q3 partials
  const int tid = threadIdx.x;
  const int cp = tid & 127;                     // columns cp, cp+128
  const int q  = tid >> 7;                      // k-quarter
  const int n0 = blockIdx.x * 8;
  const int C0 = cp, C1 = cp + 128;

  const float bir0 = bih[C0], bhr0 = bhh[C0];
  const float biz0 = bih[Hh + C0], bhz0 = bhh[Hh + C0];
  const float bin0 = bih[2 * Hh + C0], bhn0 = bhh[2 * Hh + C0];
  const float bir1 = bih[C1], bhr1 = bhh[C1];
  const float biz1 = bih[Hh + C1], bhz1 = bhh[Hh + C1];
  const float bin1 = bih[2 * Hh + C1], bhn1 = bhh[2 * Hh + C1];
  int L[8];
  #pragma unroll
  for (int r = 0; r < 8; ++r) L[r] = len[n0 + r];

  const int q16 = q * 16;
  const size_t cp4 = (size_t)cp * 4;
  const int prow = tid >> 6, pc4 = tid & 63;    // x-staging slot (1 f4/thread)

  if (tid < 256) {
    #pragma unroll
    for (int r = 0; r < 8; ++r) hls[r][tid] = 0.f;
  }
  // stage x_0
  *(float4*)&xls[prow][pc4 * 4] =
      *(const float4*)&x[(size_t)(n0 + prow) * (Tt * Dd) + pc4 * 4];
  __syncthreads();

  for (int t = 0; t < Tt; ++t) {
    // prefetch x_{t+1} into registers (latency hides under phases A+B)
    float4 xp;
    const bool havep = (t + 1 < Tt);
    if (havep)
      xp = *(const float4*)&x[(size_t)(n0 + prow) * (Tt * Dd)
                              + (size_t)(t + 1) * Dd + pc4 * 4];

    v2f aR[8][2] = {}, aZ[8][2] = {}, aXN[8][2] = {}, aHN[8][2] = {};

    // ---- phase A: gx partials over k-quarter (k ascending) ----
    #pragma unroll 2
    for (int i = 0; i < 16; ++i) {
      const int k4 = q16 + i;
      const float* pb = pk + (size_t)k4 * 6144 + cp4;
      float4 wr0 = *(const float4*)(pb);
      float4 wr1 = *(const float4*)(pb + 512);
      float4 wz0 = *(const float4*)(pb + 1024);
      float4 wz1 = *(const float4*)(pb + 1536);
      float4 wn0 = *(const float4*)(pb + 2048);
      float4 wn1 = *(const float4*)(pb + 2560);
      const int k = k4 * 4;
      #pragma unroll
      for (int r = 0; r < 8; ++r) {
        float4 xv = *(const float4*)&xls[r][k];
        v2f xlo = LO2(xv), xhi = HI2(xv);
        PKFMA(aR[r][0],  xlo, LO2(wr0)); PKFMA(aR[r][0],  xhi, HI2(wr0));
        PKFMA(aR[r][1],  xlo, LO2(wr1)); PKFMA(aR[r][1],  xhi, HI2(wr1));
        PKFMA(aZ[r][0],  xlo, LO2(wz0)); PKFMA(aZ[r][0],  xhi, HI2(wz0));
        PKFMA(aZ[r][1],  xlo, LO2(wz1)); PKFMA(aZ[r][1],  xhi, HI2(wz1));
        PKFMA(aXN[r][0], xlo, LO2(wn0)); PKFMA(aXN[r][0], xhi, HI2(wn0));
        PKFMA(aXN[r][1], xlo, LO2(wn1)); PKFMA(aXN[r][1], xhi, HI2(wn1));
      }
    }
    // ---- phase B: gh partials over k-quarter ----
    #pragma unroll 2
    for (int i = 0; i < 16; ++i) {
      const int k4 = q16 + i;
      const float* pb = pk + (size_t)k4 * 6144 + 3072 + cp4;
      float4 wr0 = *(const float4*)(pb);
      float4 wr1 = *(const float4*)(pb + 512);
      float4 wz0 = *(const float4*)(pb + 1024);
      float4 wz1 = *(const float4*)(pb + 1536);
      float4 wn0 = *(const float4*)(pb + 2048);
      float4 wn1 = *(const float4*)(pb + 2560);
      const int k = k4 * 4;
      #pragma unroll
      for (int r = 0; r < 8; ++r) {
        float4 hv = *(const float4*)&hls[r][k];
        v2f hlo = LO2(hv), hhi = HI2(hv);
        PKFMA(aR[r][0],  hlo, LO2(wr0)); PKFMA(aR[r][0],  hhi, HI2(wr0));
        PKFMA(aR[r][1],  hlo, LO2(wr1)); PKFMA(aR[r][1],  hhi, HI2(wr1));
        PKFMA(aZ[r][0],  hlo, LO2(wz0)); PKFMA(aZ[r][0],  hhi, HI2(wz0));
        PKFMA(aZ[r][1],  hlo, LO2(wz1)); PKFMA(aZ[r][1],  hhi, HI2(wz1));
        PKFMA(aHN[r][0], hlo, LO2(wn0)); PKFMA(aHN[r][0], hhi, HI2(wn0));
        PKFMA(aHN[r][1], hlo, LO2(wn1)); PKFMA(aHN[r][1], hhi, HI2(wn1));
      }
    }

    // ---- fold even/odd-k lanes to scalars (identical to r12/r14) ----
    float fR[8][2], fZ[8][2], fX[8][2], fH[8][2];
    #pragma unroll
    for (int r = 0; r < 8; ++r) {
      fR[r][0] = aR[r][0].x + aR[r][0].y;  fR[r][1] = aR[r][1].x + aR[r][1].y;
      fZ[r][0] = aZ[r][0].x + aZ[r][0].y;  fZ[r][1] = aZ[r][1].x + aZ[r][1].y;
      fX[r][0] = aXN[r][0].x + aXN[r][0].y; fX[r][1] = aXN[r][1].x + aXN[r][1].y;
      fH[r][0] = aHN[r][0].x + aHN[r][0].y; fH[r][1] = aHN[r][1].x + aHN[r][1].y;
    }

    // ---- partials out: q1->pbA, q2->pbB, q3->pbC ----
    if (q == 1) {
      #pragma unroll
      for (int r = 0; r < 8; ++r) {
        pbA[r][C0] = make_float4(fR[r][0], fZ[r][0], fX[r][0], fH[r][0]);
        pbA[r][C1] = make_float4(fR[r][1], fZ[r][1], fX[r][1], fH[r][1]);
      }
    } else if (q == 2) {
      #pragma unroll
      for (int r = 0; r < 8; ++r) {
        pbB[r][C0] = make_float4(fR[r][0], fZ[r][0], fX[r][0], fH[r][0]);
        pbB[r][C1] = make_float4(fR[r][1], fZ[r][1], fX[r][1], fH[r][1]);
      }
    } else if (q == 3) {
      #pragma unroll
      for (int r = 0; r < 8; ++r) {
        pbC[r][C0] = make_float4(fR[r][0], fZ[r][0], fX[r][0], fH[r][0]);
        pbC[r][C1] = make_float4(fR[r][1], fZ[r][1], fX[r][1], fH[r][1]);
      }
    }
    __syncthreads();                              // SYNC 1

    // ---- gates (q==0): s = (q0+q1) + (q2+q3), bit-exact vs r12 tree ----
    if (q == 0) {
      #pragma unroll
      for (int r = 0; r < 8; ++r) {
        if (t < L[r]) {
          float4 p1a = pbA[r][C0], p2a = pbB[r][C0], p3a = pbC[r][C0];
          float4 p1b = pbA[r][C1], p2b = pbB[r][C1], p3b = pbC[r][C1];
          float sR0 = (fR[r][0] + p1a.x) + (p2a.x + p3a.x);
          float sZ0 = (fZ[r][0] + p1a.y) + (p2a.y + p3a.y);
          float sX0 = (fX[r][0] + p1a.z) + (p2a.z + p3a.z);
          float sH0 = (fH[r][0] + p1a.w) + (p2a.w + p3a.w);
          float sR1 = (fR[r][1] + p1b.x) + (p2b.x + p3b.x);
          float sZ1 = (fZ[r][1] + p1b.y) + (p2b.y + p3b.y);
          float sX1 = (fX[r][1] + p1b.z) + (p2b.z + p3b.z);
          float sH1 = (fH[r][1] + p1b.w) + (p2b.w + p3b.w);
          float rg0 = sigm(sR0 + bir0 + bhr0);
          float zg0 = sigm(sZ0 + biz0 + bhz0);
          float ng0 = tanhf(sX0 + bin0 + rg0 * (sH0 + bhn0));
          float hv0 = (1.f - zg0) * ng0 + zg0 * hls[r][C0];
          float rg1 = sigm(sR1 + bir1 + bhr1);
          float zg1 = sigm(sZ1 + biz1 + bhz1);
          float ng1 = tanhf(sX1 + bin1 + rg1 * (sH1 + bhn1));
          float hv1 = (1.f - zg1) * ng1 + zg1 * hls[r][C1];
          hls[r][C0] = hv0;
          hls[r][C1] = hv1;
          if (t == L[r] - 1) {
            hfin[(size_t)(n0 + r) * Hh + C0] = hv0;
            hfin[(size_t)(n0 + r) * Hh + C1] = hv1;
          }
        }
      }
    }
    // write prefetched x_{t+1} (xls readers finished before SYNC 1)
    if (havep) *(float4*)&xls[prow][pc4 * 4] = xp;
    __syncthreads();                              // SYNC 2
  }
}

// ---------------------------------------------------------------------------
__global__ void km_init(const float* __restrict__ dat, float* __restrict__ cent, IdxArgs ia)
{
  int c = threadIdx.x;
  #pragma unroll
  for (int k = 0; k < Kk; ++k)
    cent[k * Hh + c] = dat[(size_t)ia.v[k] * Hh + c];
}

// One Lloyd iteration: assign (verbatim r12 math) + ticket-elected last-block
// update (fixed p-order reduction, bit-identical to r12's km_update).
__global__ __launch_bounds__(256) void km_iter(
    const float* __restrict__ dat, float* __restrict__ cent,
    float* __restrict__ part, int* __restrict__ pcnt, int* __restrict__ ticket)
{
  __shared__ alignas(16) float cs[Kk][Hh];        // centers
  __shared__ alignas(16) float ps[4][Kk][Hh];     // per-wave partial sums
  __shared__ float c2s[Kk];
  __shared__ int pc[4][Kk];
  __shared__ int lastflag;
  const int tid = threadIdx.x;
  const int lane = tid & 63;
  const int w = tid >> 6;

  for (int i = tid; i < Kk * Hh; i += 256) ((float*)cs)[i] = cent[i];
  for (int i = tid; i < 4 * Kk * Hh; i += 256) ((float*)ps)[i] = 0.f;
  if (tid < 4 * Kk) ((int*)pc)[tid] = 0;
  __syncthreads();
  if (tid < Kk) {
    float s = 0.f;
    for (int c = 0; c < Hh; ++c) { float v = cs[tid][c]; s += v * v; }
    c2s[tid] = s;
  }
  __syncthreads();

  const int base = blockIdx.x * 64 + w * 16;      // 16 rows per wave
  for (int rr = 0; rr < 16; ++rr) {
    const int n = base + rr;
    float4 v = *(const float4*)&dat[(size_t)n * Hh + lane * 4];
    float best = 3.4e38f; int bi = 0;
    #pragma unroll
    for (int k = 0; k < Kk; ++k) {
      float4 cv = *(const float4*)&cs[k][lane * 4];
      float p = v.x * cv.x + v.y * cv.y + v.z * cv.z + v.w * cv.w;
      #pragma unroll
      for (int m = 1; m < 64; m <<= 1) p += __shfl_xor(p, m, 64);
      float d = c2s[k] - 2.f * p;                 // x^2 constant per row
      if (d < best) { best = d; bi = k; }         // strict <: first-min = argmin
    }
    float4* dst = (float4*)&ps[w][bi][lane * 4];
    float4 cur = *dst;
    cur.x += v.x; cur.y += v.y; cur.z += v.z; cur.w += v.w;
    *dst = cur;
    if (lane == 0) pc[w][bi] += 1;
  }
  __syncthreads();
  const float* p0 = &ps[0][0][0];
  for (int i = tid; i < Kk * Hh; i += 256)
    part[(size_t)blockIdx.x * (Kk * Hh) + i] =
        p0[i] + p0[Kk * Hh + i] + p0[2 * Kk * Hh + i] + p0[3 * Kk * Hh + i];
  if (tid < Kk)
    pcnt[blockIdx.x * Kk + tid] = pc[0][tid] + pc[1][tid] + pc[2][tid] + pc[3][tid];

  // ---- last-block update (same fence+atomic mechanism as grid.sync) ----
  __threadfence();
  if (tid == 0) lastflag = (atomicAdd(ticket, 1) == 31);
  __syncthreads();
  if (lastflag) {
    __threadfence();                              // acquire
    const int c = tid;
    #pragma unroll
    for (int k = 0; k < Kk; ++k) {
      int cnt = 0;
      for (int p = 0; p < 32; ++p) cnt += pcnt[p * Kk + k];
      float s = 0.f;
      for (int p = 0; p < 32; ++p) s += part[(size_t)p * (Kk * Hh) + k * Hh + c];
      if (cnt > 0) cent[k * Hh + c] = s / (float)cnt;
    }
  }
}

// ---------------------------------------------------------------------------
// h1 = relu(centers@g1_w + g1_b); h2 = relu(h1@g2_w + g2_b). One block.
__global__ __launch_bounds__(256) void gcn(
    const float* __restrict__ cent, const float* __restrict__ g1w,
    const float* __restrict__ g1b, const float* __restrict__ g2w,
    const float* __restrict__ g2b, float* __restrict__ h2out)
{
  __shared__ float a[Kk][Hh];
  __shared__ float b[Kk][Hh];
  int c = threadIdx.x;
  for (int i = c; i < Kk * Hh; i += 256) ((float*)a)[i] = cent[i];
  __syncthreads();
  float acc[Kk];
  #pragma unroll
  for (int k = 0; k < Kk; ++k) acc[k] = 0.f;
  for (int j = 0; j < Hh; ++j) {
    float wv = g1w[(size_t)j * Hh + c];
    #pragma unroll
    for (int k = 0; k < Kk; ++k) acc[k] += a[k][j] * wv;
  }
  #pragma unroll
  for (int k = 0; k < Kk; ++k) b[k][c] = fmaxf(acc[k] + g1b[c], 0.f);
  __syncthreads();
  #pragma unroll
  for (int k = 0; k < Kk; ++k) acc[k] = 0.f;
  for (int j = 0; j < Hh; ++j) {
    float wv = g2w[(size_t)j * Hh + c];
    #pragma unroll
    for (int k = 0; k < Kk; ++k) acc[k] += b[k][j] * wv;
  }
  #pragma unroll
  for (int k = 0; k < Kk; ++k) h2out[k * Hh + c] = fmaxf(acc[k] + g2b[c], 0.f);
}

// scores = softmax(relu(ht@centers^T)); clu = scores@h2; gated blend. 1 block/row.
__global__ __launch_bounds__(256) void finalk(
    const float* __restrict__ hfin, const float* __restrict__ cent,
    const float* __restrict__ h2, const float* __restrict__ w1w,
    const float* __restrict__ w1b, const float* __restrict__ w2w,
    const float* __restrict__ w2b, float* __restrict__ out)
{
  __shared__ alignas(16) float cs[Kk][Hh];
  __shared__ alignas(16) float hs[Kk][Hh];
  __shared__ float red[4];
  const int tid = threadIdx.x, lane = tid & 63, w = tid >> 6;
  const int n = blockIdx.x;
  for (int i = tid; i < Kk * Hh; i += 256) { ((float*)cs)[i] = cent[i]; ((float*)hs)[i] = h2[i]; }
  float ht = hfin[(size_t)n * Hh + tid];
  __syncthreads();

  auto bred = [&](float v) -> float {
    #pragma unroll
    for (int m = 1; m < 64; m <<= 1) v += __shfl_xor(v, m, 64);
    __syncthreads();
    if (lane == 0) red[w] = v;
    __syncthreads();
    return red[0] + red[1] + red[2] + red[3];
  };

  float ev[Kk];
  #pragma unroll
  for (int k = 0; k < Kk; ++k)
    ev[k] = fmaxf(bred(ht * cs[k][tid]), 0.f);

  float mx = ev[0];
  #pragma unroll
  for (int k = 1; k < Kk; ++k) mx = fmaxf(mx, ev[k]);
  float se = 0.f; float sc[Kk];
  #pragma unroll
  for (int k = 0; k < Kk; ++k) { sc[k] = expf(ev[k] - mx); se += sc[k]; }
  float inv = 1.f / se;
  float clu = 0.f;
  #pragma unroll
  for (int k = 0; k < Kk; ++k) clu += sc[k] * inv * hs[k][tid];

  float r1 = bred(clu * w1w[tid]);
  float r2 = bred(ht * w2w[tid]);
  float a1 = sigm(r1 + w1b[0]);
  float a2 = sigm(r2 + w2b[0]);
  float wn = a1 / (a1 + a2);
  out[(size_t)n * Hh + tid] = wn * clu + (1.f - wn) * ht;
}

// ---------------------------------------------------------------------------
// Host-side threefry2x32 (JAX), reproducing jax.random.permutation(key(42), 2048)[:12].
static void tf2x32(uint32_t k0, uint32_t k1, uint32_t c0, uint32_t c1,
                   uint32_t& o0, uint32_t& o1) {
  uint32_t ks2 = k0 ^ k1 ^ 0x1BD11BDAu;
  uint32_t x0 = c0 + k0, x1 = c1 + k1;
#define TFR(r) do { x0 += x1; x1 = (x1 << (r)) | (x1 >> (32 - (r))); x1 ^= x0; } while (0)
  TFR(13); TFR(15); TFR(26); TFR(6);
  x0 += k1;  x1 += ks2 + 1u;
  TFR(17); TFR(29); TFR(16); TFR(24);
  x0 += ks2; x1 += k0 + 2u;
  TFR(13); TFR(15); TFR(26); TFR(6);
  x0 += k0;  x1 += k1 + 3u;
  TFR(17); TFR(29); TFR(16); TFR(24);
  x0 += k1;  x1 += ks2 + 4u;
  TFR(13); TFR(15); TFR(26); TFR(6);
  x0 += ks2; x1 += k0 + 5u;
#undef TFR
  o0 = x0; o1 = x1;
}

static void compute_idx(int* out12) {
  uint32_t kh = 0u, kl = 42u;     // jax.random.key(42) -> (0, 42)
  std::vector<int> perm(Nn);
  for (int i = 0; i < Nn; ++i) perm[i] = i;
  std::vector<uint32_t> bits(Nn);
  std::vector<int> pos(Nn);
  for (int round = 0; round < 2; ++round) {     // 2 rounds for n=2048
    uint32_t nh, nl, sh, sl;
    tf2x32(kh, kl, 0u, 0u, nh, nl);             // split: counters (0,0),(0,1)
    tf2x32(kh, kl, 0u, 1u, sh, sl);
    kh = nh; kl = nl;
    // partitionable random_bits(32): bits[i] = o0 ^ o1 at counter (0, i)
    for (uint32_t i = 0; i < (uint32_t)Nn; ++i) {
      uint32_t o0, o1; tf2x32(sh, sl, 0u, i, o0, o1); bits[i] = o0 ^ o1;
    }
    for (int i = 0; i < Nn; ++i) pos[i] = i;
    std::stable_sort(pos.begin(), pos.end(),
                     [&](int a, int b) { return bits[a] < bits[b]; });
    std::vector<int> np(Nn);
    for (int i = 0; i < Nn; ++i) np[i] = perm[pos[i]];
    perm.swap(np);
  }
  for (int k = 0; k < Kk; ++k) out12[k] = perm[k];
}

// ---------------------------------------------------------------------------
extern "C" void kernel_launch(void* const* d_in, const int* in_sizes, int n_in,
                              void* d_out, int out_size, void* d_ws, size_t ws_size,
                              hipStream_t stream) {
  const float* x   = (const float*)d_in[0];
  const int*   len = (const int*)d_in[1];
  const float* Wih = (const float*)d_in[2];
  const float* Whh = (const float*)d_in[3];
  const float* bih = (const float*)d_in[4];
  const float* bhh = (const float*)d_in[5];
  const float* w1w = (const float*)d_in[6];
  const float* w1b = (const float*)d_in[7];
  const float* w2w = (const float*)d_in[8];
  const float* w2b = (const float*)d_in[9];
  const float* g1w = (const float*)d_in[10];
  const float* g1b = (const float*)d_in[11];
  const float* g2w = (const float*)d_in[12];
  const float* g2b = (const float*)d_in[13];
  float* out = (float*)d_out;

  float* wsf  = (float*)d_ws;
  float* hfin = wsf;                           // N*H
  float* cent = hfin + (size_t)Nn * Hh;        // K*H
  float* h2g  = cent + Kk * Hh;                // K*H
  float* part = h2g + Kk * Hh;                 // 32*K*H
  int*   pcnt = (int*)(part + 32 * Kk * Hh);   // 32*K ints (pad to 512)
  int*   ticket = pcnt + 512;                  // MAXIT ints (pad to 128)
  float* pkw  = (float*)(ticket + 128);        // 393216 floats, 16B-aligned

  IdxArgs ia;
  compute_idx(ia.v);                           // host, deterministic, capture-safe

  hipMemsetAsync(ticket, 0, MAXIT * sizeof(int), stream);   // capture-safe
  pack_w<<<768, 64, 0, stream>>>(Wih, Whh, pkw);
  gru_q<<<256, 512, 0, stream>>>(x, len, pkw, bih, bhh, hfin);

  km_init<<<1, 256, 0, stream>>>(hfin, cent, ia);
  for (int it = 0; it < MAXIT; ++it)
    km_iter<<<32, 256, 0, stream>>>(hfin, cent, part, pcnt, ticket + it);

  gcn<<<1, 256, 0, stream>>>(cent, g1w, g1b, g2w, g2b, h2g);
  finalk<<<Nn, 256, 0, stream>>>(hfin, cent, h2g, w1w, w1b, w2w, w2b, out);
}

// Round 17
// 4663.959 us; speedup vs baseline: 1.6950x; 1.6950x over previous
//
#include <hip/hip_runtime.h>
#include <cstdint>
#include <cstring>
#include <vector>
#include <algorithm>

// ---------------------------------------------------------------------------
// GRASPLayer round 17: best-measured assembly.
//  - GRU: r15 verbatim (4-sync, asm v_pk_fma_f32, 3.36 ms best).
//  - kmeans: r12 verbatim two-kernel scheme + convergence skip: chg[it] set
//    when any code changes; done=1 at the Lloyd fixed point; post-convergence
//    dispatches early-return (launch-only no-ops). Output bitwise unchanged.
// ---------------------------------------------------------------------------

namespace {
constexpr int Nn = 2048;
constexpr int Tt = 128;
constexpr int Dd = 256;
constexpr int Hh = 256;
constexpr int Kk = 12;
constexpr int MAXIT = 100;
}

struct IdxArgs { int v[Kk]; };

typedef float v2f __attribute__((ext_vector_type(2)));

__device__ __forceinline__ float sigm(float x) { return 1.0f / (1.0f + expf(-x)); }

#define PKFMA(A, X, W) \
  asm("v_pk_fma_f32 %0, %1, %2, %0" : "+v"(A) : "v"(X), "v"(W))
#define LO2(V) ((v2f){(V).x, (V).y})
#define HI2(V) ((v2f){(V).z, (V).w})

// ---------------------------------------------------------------------------
// Pack Wih/Whh [3*256 x 256] into pk[k4][g][c][4] (float4 = 4 adjacent k of
// column c), g in {ihr,ihz,ihn,hhr,hhz,hhn}.
__global__ __launch_bounds__(64) void pack_w(
    const float* __restrict__ Wih, const float* __restrict__ Whh,
    float* __restrict__ pk)
{
  const int j = blockIdx.x;            // 0..767 = w-row (g*256 + c)
  const int k4 = threadIdx.x;          // 0..63
  const int g = j >> 8, c = j & 255;
  float4 vih = *(const float4*)&Wih[(size_t)j * 256 + k4 * 4];
  float4 vhh = *(const float4*)&Whh[(size_t)j * 256 + k4 * 4];
  *(float4*)&pk[(((size_t)k4 * 6 + g) * 256 + c) * 4]       = vih;
  *(float4*)&pk[(((size_t)k4 * 6 + 3 + g) * 256 + c) * 4]   = vhh;
}

// ---------------------------------------------------------------------------
// GRU (verbatim r15 PASS): 256 blocks x 512 threads; block owns 8 rows.
// Thread (cp, q) accumulates cols {cp, cp+128} over k-quarter q.
__global__ __launch_bounds__(512, 1) void gru_q(
    const float* __restrict__ x, const int* __restrict__ len,
    const float* __restrict__ pk,
    const float* __restrict__ bih, const float* __restrict__ bhh,
    float* __restrict__ hfin)
{
  __shared__ alignas(16) float xls[8][260];
  __shared__ alignas(16) float hls[8][260];
  __shared__ float4 pbuf[2][8][256];            // 64 KB combine buffer
  const int tid = threadIdx.x;
  const int cp = tid & 127;                     // columns cp, cp+128
  const int q  = tid >> 7;                      // k-quarter
  const int n0 = blockIdx.x * 8;
  const int C0 = cp, C1 = cp + 128;

  const float bir0 = bih[C0], bhr0 = bhh[C0];
  const float biz0 = bih[Hh + C0], bhz0 = bhh[Hh + C0];
  const float bin0 = bih[2 * Hh + C0], bhn0 = bhh[2 * Hh + C0];
  const float bir1 = bih[C1], bhr1 = bhh[C1];
  const float biz1 = bih[Hh + C1], bhz1 = bhh[Hh + C1];
  const float bin1 = bih[2 * Hh + C1], bhn1 = bhh[2 * Hh + C1];
  int L[8];
  #pragma unroll
  for (int r = 0; r < 8; ++r) L[r] = len[n0 + r];

  const int q16 = q * 16;
  const size_t cp4 = (size_t)cp * 4;

  if (tid < 256) {
    #pragma unroll
    for (int r = 0; r < 8; ++r) hls[r][tid] = 0.f;
  }

  for (int t = 0; t < Tt; ++t) {
    {
      int row = tid >> 6, c4 = tid & 63;
      *(float4*)&xls[row][c4 * 4] =
          *(const float4*)&x[(size_t)(n0 + row) * (Tt * Dd) + (size_t)t * Dd + c4 * 4];
    }
    __syncthreads();

    v2f aR[8][2] = {}, aZ[8][2] = {}, aXN[8][2] = {}, aHN[8][2] = {};

    #pragma unroll 1
    for (int i = 0; i < 16; ++i) {
      const int k4 = q16 + i;
      const float* pb = pk + (size_t)k4 * 6144 + cp4;
      float4 wr0 = *(const float4*)(pb);
      float4 wr1 = *(const float4*)(pb + 512);
      float4 wz0 = *(const float4*)(pb + 1024);
      float4 wz1 = *(const float4*)(pb + 1536);
      float4 wn0 = *(const float4*)(pb + 2048);
      float4 wn1 = *(const float4*)(pb + 2560);
      const int k = k4 * 4;
      #pragma unroll
      for (int r = 0; r < 8; ++r) {
        float4 xv = *(const float4*)&xls[r][k];
        v2f xlo = LO2(xv), xhi = HI2(xv);
        PKFMA(aR[r][0],  xlo, LO2(wr0)); PKFMA(aR[r][0],  xhi, HI2(wr0));
        PKFMA(aR[r][1],  xlo, LO2(wr1)); PKFMA(aR[r][1],  xhi, HI2(wr1));
        PKFMA(aZ[r][0],  xlo, LO2(wz0)); PKFMA(aZ[r][0],  xhi, HI2(wz0));
        PKFMA(aZ[r][1],  xlo, LO2(wz1)); PKFMA(aZ[r][1],  xhi, HI2(wz1));
        PKFMA(aXN[r][0], xlo, LO2(wn0)); PKFMA(aXN[r][0], xhi, HI2(wn0));
        PKFMA(aXN[r][1], xlo, LO2(wn1)); PKFMA(aXN[r][1], xhi, HI2(wn1));
      }
    }
    #pragma unroll 1
    for (int i = 0; i < 16; ++i) {
      const int k4 = q16 + i;
      const float* pb = pk + (size_t)k4 * 6144 + 3072 + cp4;
      float4 wr0 = *(const float4*)(pb);
      float4 wr1 = *(const float4*)(pb + 512);
      float4 wz0 = *(const float4*)(pb + 1024);
      float4 wz1 = *(const float4*)(pb + 1536);
      float4 wn0 = *(const float4*)(pb + 2048);
      float4 wn1 = *(const float4*)(pb + 2560);
      const int k = k4 * 4;
      #pragma unroll
      for (int r = 0; r < 8; ++r) {
        float4 hv = *(const float4*)&hls[r][k];
        v2f hlo = LO2(hv), hhi = HI2(hv);
        PKFMA(aR[r][0],  hlo, LO2(wr0)); PKFMA(aR[r][0],  hhi, HI2(wr0));
        PKFMA(aR[r][1],  hlo, LO2(wr1)); PKFMA(aR[r][1],  hhi, HI2(wr1));
        PKFMA(aZ[r][0],  hlo, LO2(wz0)); PKFMA(aZ[r][0],  hhi, HI2(wz0));
        PKFMA(aZ[r][1],  hlo, LO2(wz1)); PKFMA(aZ[r][1],  hhi, HI2(wz1));
        PKFMA(aHN[r][0], hlo, LO2(wn0)); PKFMA(aHN[r][0], hhi, HI2(wn0));
        PKFMA(aHN[r][1], hlo, LO2(wn1)); PKFMA(aHN[r][1], hhi, HI2(wn1));
      }
    }

    float fR[8][2], fZ[8][2], fX[8][2], fH[8][2];
    #pragma unroll
    for (int r = 0; r < 8; ++r) {
      fR[r][0] = aR[r][0].x + aR[r][0].y;  fR[r][1] = aR[r][1].x + aR[r][1].y;
      fZ[r][0] = aZ[r][0].x + aZ[r][0].y;  fZ[r][1] = aZ[r][1].x + aZ[r][1].y;
      fX[r][0] = aXN[r][0].x + aXN[r][0].y; fX[r][1] = aXN[r][1].x + aXN[r][1].y;
      fH[r][0] = aHN[r][0].x + aHN[r][0].y; fH[r][1] = aHN[r][1].x + aHN[r][1].y;
    }

    if (q == 1 || q == 3) {
      const int reg = q >> 1;
      #pragma unroll
      for (int r = 0; r < 8; ++r) {
        pbuf[reg][r][C0] = make_float4(fR[r][0], fZ[r][0], fX[r][0], fH[r][0]);
        pbuf[reg][r][C1] = make_float4(fR[r][1], fZ[r][1], fX[r][1], fH[r][1]);
      }
    }
    __syncthreads();
    if (q == 0 || q == 2) {
      const int reg = q >> 1;
      #pragma unroll
      for (int r = 0; r < 8; ++r) {
        float4 p0 = pbuf[reg][r][C0];
        float4 p1 = pbuf[reg][r][C1];
        fR[r][0] += p0.x; fZ[r][0] += p0.y; fX[r][0] += p0.z; fH[r][0] += p0.w;
        fR[r][1] += p1.x; fZ[r][1] += p1.y; fX[r][1] += p1.z; fH[r][1] += p1.w;
      }
    }
    __syncthreads();
    if (q == 2) {
      #pragma unroll
      for (int r = 0; r < 8; ++r) {
        pbuf[0][r][C0] = make_float4(fR[r][0], fZ[r][0], fX[r][0], fH[r][0]);
        pbuf[0][r][C1] = make_float4(fR[r][1], fZ[r][1], fX[r][1], fH[r][1]);
      }
    }
    __syncthreads();

    if (q == 0) {
      #pragma unroll
      for (int r = 0; r < 8; ++r) {
        if (t < L[r]) {
          float4 p0 = pbuf[0][r][C0];
          float4 p1 = pbuf[0][r][C1];
          float sR0 = fR[r][0] + p0.x, sZ0 = fZ[r][0] + p0.y;
          float sX0 = fX[r][0] + p0.z, sH0 = fH[r][0] + p0.w;
          float sR1 = fR[r][1] + p1.x, sZ1 = fZ[r][1] + p1.y;
          float sX1 = fX[r][1] + p1.z, sH1 = fH[r][1] + p1.w;
          float rg0 = sigm(sR0 + bir0 + bhr0);
          float zg0 = sigm(sZ0 + biz0 + bhz0);
          float ng0 = tanhf(sX0 + bin0 + rg0 * (sH0 + bhn0));
          float hv0 = (1.f - zg0) * ng0 + zg0 * hls[r][C0];
          float rg1 = sigm(sR1 + bir1 + bhr1);
          float zg1 = sigm(sZ1 + biz1 + bhz1);
          float ng1 = tanhf(sX1 + bin1 + rg1 * (sH1 + bhn1));
          float hv1 = (1.f - zg1) * ng1 + zg1 * hls[r][C1];
          hls[r][C0] = hv0;
          hls[r][C1] = hv1;
          if (t == L[r] - 1) {
            hfin[(size_t)(n0 + r) * Hh + C0] = hv0;
            hfin[(size_t)(n0 + r) * Hh + C1] = hv1;
          }
        }
      }
    }
    __syncthreads();
  }
}

// ---------------------------------------------------------------------------
__global__ void km_init(const float* __restrict__ dat, float* __restrict__ cent,
                        int* __restrict__ codes_prev, IdxArgs ia)
{
  int c = threadIdx.x;
  #pragma unroll
  for (int k = 0; k < Kk; ++k)
    cent[k * Hh + c] = dat[(size_t)ia.v[k] * Hh + c];
  #pragma unroll
  for (int i = 0; i < 8; ++i) codes_prev[i * 256 + c] = -1;
}

// Assign + per-block partial sums (verbatim r12 math) + change detection.
// Early-return once converged (done set): launch-only no-op.
__global__ __launch_bounds__(256) void km_assign(
    const float* __restrict__ dat, const float* __restrict__ cent,
    float* __restrict__ part, int* __restrict__ pcnt,
    int* __restrict__ codes_prev, int* __restrict__ chg_it,
    const int* __restrict__ done)
{
  if (done[0]) return;                            // fixed point reached
  __shared__ alignas(16) float cs[Kk][Hh];        // centers
  __shared__ alignas(16) float ps[4][Kk][Hh];     // per-wave partial sums
  __shared__ float c2s[Kk];
  __shared__ int pc[4][Kk];
  __shared__ int chg_l;
  const int tid = threadIdx.x;
  const int lane = tid & 63;
  const int w = tid >> 6;

  for (int i = tid; i < Kk * Hh; i += 256) ((float*)cs)[i] = cent[i];
  for (int i = tid; i < 4 * Kk * Hh; i += 256) ((float*)ps)[i] = 0.f;
  if (tid < 4 * Kk) ((int*)pc)[tid] = 0;
  if (tid == 0) chg_l = 0;
  __syncthreads();
  if (tid < Kk) {
    float s = 0.f;
    for (int c = 0; c < Hh; ++c) { float v = cs[tid][c]; s += v * v; }
    c2s[tid] = s;
  }
  __syncthreads();

  int mych = 0;
  const int base = blockIdx.x * 64 + w * 16;      // 16 rows per wave
  for (int rr = 0; rr < 16; ++rr) {
    const int n = base + rr;
    float4 v = *(const float4*)&dat[(size_t)n * Hh + lane * 4];
    float best = 3.4e38f; int bi = 0;
    #pragma unroll
    for (int k = 0; k < Kk; ++k) {
      float4 cv = *(const float4*)&cs[k][lane * 4];
      float p = v.x * cv.x + v.y * cv.y + v.z * cv.z + v.w * cv.w;
      #pragma unroll
      for (int m = 1; m < 64; m <<= 1) p += __shfl_xor(p, m, 64);
      float d = c2s[k] - 2.f * p;                 // x^2 constant per row
      if (d < best) { best = d; bi = k; }         // strict <: first-min = argmin
    }
    float4* dst = (float4*)&ps[w][bi][lane * 4];
    float4 cur = *dst;
    cur.x += v.x; cur.y += v.y; cur.z += v.z; cur.w += v.w;
    *dst = cur;
    if (lane == 0) {
      pc[w][bi] += 1;
      if (codes_prev[n] != bi) { codes_prev[n] = bi; mych = 1; }
    }
  }
  if (mych) atomicOr(&chg_l, 1);
  __syncthreads();
  const float* p0 = &ps[0][0][0];
  for (int i = tid; i < Kk * Hh; i += 256)
    part[(size_t)blockIdx.x * (Kk * Hh) + i] =
        p0[i] + p0[Kk * Hh + i] + p0[2 * Kk * Hh + i] + p0[3 * Kk * Hh + i];
  if (tid < Kk)
    pcnt[blockIdx.x * Kk + tid] = pc[0][tid] + pc[1][tid] + pc[2][tid] + pc[3][tid];
  if (tid == 0 && chg_l) atomicOr(chg_it, 1);
}

// Reduce 32 block-partials in fixed order (verbatim r12); set done at the
// fixed point; early-return once converged.
__global__ __launch_bounds__(256) void km_update(
    const float* __restrict__ part, const int* __restrict__ pcnt,
    float* __restrict__ cent, const int* __restrict__ chg_it,
    int* __restrict__ done)
{
  if (done[0]) return;
  int k = blockIdx.x, c = threadIdx.x;
  int cnt = 0;
  for (int p = 0; p < 32; ++p) cnt += pcnt[p * Kk + k];
  float s = 0.f;
  for (int p = 0; p < 32; ++p) s += part[(size_t)p * (Kk * Hh) + k * Hh + c];
  if (cnt > 0) cent[k * Hh + c] = s / (float)cnt;
  // codes unchanged this iter -> centers are at the Lloyd fixed point;
  // all remaining iterations are bitwise no-ops -> skip them.
  if (k == 0 && c == 0 && chg_it[0] == 0) done[0] = 1;
}

// ---------------------------------------------------------------------------
// h1 = relu(centers@g1_w + g1_b); h2 = relu(h1@g2_w + g2_b). One block.
__global__ __launch_bounds__(256) void gcn(
    const float* __restrict__ cent, const float* __restrict__ g1w,
    const float* __restrict__ g1b, const float* __restrict__ g2w,
    const float* __restrict__ g2b, float* __restrict__ h2out)
{
  __shared__ float a[Kk][Hh];
  __shared__ float b[Kk][Hh];
  int c = threadIdx.x;
  for (int i = c; i < Kk * Hh; i += 256) ((float*)a)[i] = cent[i];
  __syncthreads();
  float acc[Kk];
  #pragma unroll
  for (int k = 0; k < Kk; ++k) acc[k] = 0.f;
  for (int j = 0; j < Hh; ++j) {
    float wv = g1w[(size_t)j * Hh + c];
    #pragma unroll
    for (int k = 0; k < Kk; ++k) acc[k] += a[k][j] * wv;
  }
  #pragma unroll
  for (int k = 0; k < Kk; ++k) b[k][c] = fmaxf(acc[k] + g1b[c], 0.f);
  __syncthreads();
  #pragma unroll
  for (int k = 0; k < Kk; ++k) acc[k] = 0.f;
  for (int j = 0; j < Hh; ++j) {
    float wv = g2w[(size_t)j * Hh + c];
    #pragma unroll
    for (int k = 0; k < Kk; ++k) acc[k] += b[k][j] * wv;
  }
  #pragma unroll
  for (int k = 0; k < Kk; ++k) h2out[k * Hh + c] = fmaxf(acc[k] + g2b[c], 0.f);
}

// scores = softmax(relu(ht@centers^T)); clu = scores@h2; gated blend. 1 block/row.
__global__ __launch_bounds__(256) void finalk(
    const float* __restrict__ hfin, const float* __restrict__ cent,
    const float* __restrict__ h2, const float* __restrict__ w1w,
    const float* __restrict__ w1b, const float* __restrict__ w2w,
    const float* __restrict__ w2b, float* __restrict__ out)
{
  __shared__ alignas(16) float cs[Kk][Hh];
  __shared__ alignas(16) float hs[Kk][Hh];
  __shared__ float red[4];
  const int tid = threadIdx.x, lane = tid & 63, w = tid >> 6;
  const int n = blockIdx.x;
  for (int i = tid; i < Kk * Hh; i += 256) { ((float*)cs)[i] = cent[i]; ((float*)hs)[i] = h2[i]; }
  float ht = hfin[(size_t)n * Hh + tid];
  __syncthreads();

  auto bred = [&](float v) -> float {
    #pragma unroll
    for (int m = 1; m < 64; m <<= 1) v += __shfl_xor(v, m, 64);
    __syncthreads();
    if (lane == 0) red[w] = v;
    __syncthreads();
    return red[0] + red[1] + red[2] + red[3];
  };

  float ev[Kk];
  #pragma unroll
  for (int k = 0; k < Kk; ++k)
    ev[k] = fmaxf(bred(ht * cs[k][tid]), 0.f);

  float mx = ev[0];
  #pragma unroll
  for (int k = 1; k < Kk; ++k) mx = fmaxf(mx, ev[k]);
  float se = 0.f; float sc[Kk];
  #pragma unroll
  for (int k = 0; k < Kk; ++k) { sc[k] = expf(ev[k] - mx); se += sc[k]; }
  float inv = 1.f / se;
  float clu = 0.f;
  #pragma unroll
  for (int k = 0; k < Kk; ++k) clu += sc[k] * inv * hs[k][tid];

  float r1 = bred(clu * w1w[tid]);
  float r2 = bred(ht * w2w[tid]);
  float a1 = sigm(r1 + w1b[0]);
  float a2 = sigm(r2 + w2b[0]);
  float wn = a1 / (a1 + a2);
  out[(size_t)n * Hh + tid] = wn * clu + (1.f - wn) * ht;
}

// ---------------------------------------------------------------------------
// Host-side threefry2x32 (JAX), reproducing jax.random.permutation(key(42), 2048)[:12].
static void tf2x32(uint32_t k0, uint32_t k1, uint32_t c0, uint32_t c1,
                   uint32_t& o0, uint32_t& o1) {
  uint32_t ks2 = k0 ^ k1 ^ 0x1BD11BDAu;
  uint32_t x0 = c0 + k0, x1 = c1 + k1;
#define TFR(r) do { x0 += x1; x1 = (x1 << (r)) | (x1 >> (32 - (r))); x1 ^= x0; } while (0)
  TFR(13); TFR(15); TFR(26); TFR(6);
  x0 += k1;  x1 += ks2 + 1u;
  TFR(17); TFR(29); TFR(16); TFR(24);
  x0 += ks2; x1 += k0 + 2u;
  TFR(13); TFR(15); TFR(26); TFR(6);
  x0 += k0;  x1 += k1 + 3u;
  TFR(17); TFR(29); TFR(16); TFR(24);
  x0 += k1;  x1 += ks2 + 4u;
  TFR(13); TFR(15); TFR(26); TFR(6);
  x0 += ks2; x1 += k0 + 5u;
#undef TFR
  o0 = x0; o1 = x1;
}

static void compute_idx(int* out12) {
  uint32_t kh = 0u, kl = 42u;     // jax.random.key(42) -> (0, 42)
  std::vector<int> perm(Nn);
  for (int i = 0; i < Nn; ++i) perm[i] = i;
  std::vector<uint32_t> bits(Nn);
  std::vector<int> pos(Nn);
  for (int round = 0; round < 2; ++round) {     // 2 rounds for n=2048
    uint32_t nh, nl, sh, sl;
    tf2x32(kh, kl, 0u, 0u, nh, nl);             // split: counters (0,0),(0,1)
    tf2x32(kh, kl, 0u, 1u, sh, sl);
    kh = nh; kl = nl;
    // partitionable random_bits(32): bits[i] = o0 ^ o1 at counter (0, i)
    for (uint32_t i = 0; i < (uint32_t)Nn; ++i) {
      uint32_t o0, o1; tf2x32(sh, sl, 0u, i, o0, o1); bits[i] = o0 ^ o1;
    }
    for (int i = 0; i < Nn; ++i) pos[i] = i;
    std::stable_sort(pos.begin(), pos.end(),
                     [&](int a, int b) { return bits[a] < bits[b]; });
    std::vector<int> np(Nn);
    for (int i = 0; i < Nn; ++i) np[i] = perm[pos[i]];
    perm.swap(np);
  }
  for (int k = 0; k < Kk; ++k) out12[k] = perm[k];
}

// ---------------------------------------------------------------------------
extern "C" void kernel_launch(void* const* d_in, const int* in_sizes, int n_in,
                              void* d_out, int out_size, void* d_ws, size_t ws_size,
                              hipStream_t stream) {
  const float* x   = (const float*)d_in[0];
  const int*   len = (const int*)d_in[1];
  const float* Wih = (const float*)d_in[2];
  const float* Whh = (const float*)d_in[3];
  const float* bih = (const float*)d_in[4];
  const float* bhh = (const float*)d_in[5];
  const float* w1w = (const float*)d_in[6];
  const float* w1b = (const float*)d_in[7];
  const float* w2w = (const float*)d_in[8];
  const float* w2b = (const float*)d_in[9];
  const float* g1w = (const float*)d_in[10];
  const float* g1b = (const float*)d_in[11];
  const float* g2w = (const float*)d_in[12];
  const float* g2b = (const float*)d_in[13];
  float* out = (float*)d_out;

  float* wsf  = (float*)d_ws;
  float* hfin = wsf;                            // N*H
  float* cent = hfin + (size_t)Nn * Hh;         // K*H
  float* h2g  = cent + Kk * Hh;                 // K*H
  float* part = h2g + Kk * Hh;                  // 32*K*H
  int*   pcnt = (int*)(part + 32 * Kk * Hh);    // 32*K ints (pad to 512)
  int*   codes = pcnt + 512;                    // Nn ints
  int*   chg  = codes + Nn;                     // MAXIT ints + done at [MAXIT]
  float* pkw  = (float*)(chg + MAXIT + 28);     // 393216 floats, 16B-aligned

  IdxArgs ia;
  compute_idx(ia.v);                            // host, deterministic, capture-safe

  hipMemsetAsync(chg, 0, (MAXIT + 1) * sizeof(int), stream);   // capture-safe
  pack_w<<<768, 64, 0, stream>>>(Wih, Whh, pkw);
  gru_q<<<256, 512, 0, stream>>>(x, len, pkw, bih, bhh, hfin);

  int* done = chg + MAXIT;
  km_init<<<1, 256, 0, stream>>>(hfin, cent, codes, ia);
  for (int it = 0; it < MAXIT; ++it) {
    km_assign<<<32, 256, 0, stream>>>(hfin, cent, part, pcnt, codes, chg + it, done);
    km_update<<<Kk, 256, 0, stream>>>(part, pcnt, cent, chg + it, done);
  }

  gcn<<<1, 256, 0, stream>>>(cent, g1w, g1b, g2w, g2b, h2g);
  finalk<<<Nn, 256, 0, stream>>>(hfin, cent, h2g, w1w, w1b, w2w, w2b, out);
}